// Round 1
// baseline (28408.847 us; speedup 1.0000x reference)
//
#include <hip/hip_runtime.h>
#include <cstdint>
#include <cstddef>

typedef _Float16 f16;
typedef _Float16 f16x8 __attribute__((ext_vector_type(8)));
typedef _Float16 f16x4v __attribute__((ext_vector_type(4)));
typedef float f32x4 __attribute__((ext_vector_type(4)));

#define TT 2048
#define BB 16
#define DD 1024
#define MM (TT*BB)
#define LDST 40   // padded LDS row stride (halves) to break bank conflicts

// ---------------- f32 -> f16 convert ----------------
__global__ void cvt_kernel(const float* __restrict__ in, f16* __restrict__ out, int n4){
  int stride = gridDim.x * blockDim.x;
  for (int j = blockIdx.x*blockDim.x + threadIdx.x; j < n4; j += stride){
    float4 v = ((const float4*)in)[j];
    f16x4v o;
    o[0]=(f16)v.x; o[1]=(f16)v.y; o[2]=(f16)v.z; o[3]=(f16)v.w;
    ((f16x4v*)out)[j] = o;
  }
}

// ---------------- recurrence init: zero flags, h0 -> hbuf[0] ----------------
__global__ void init_rec_kernel(const float* __restrict__ h0, f16* __restrict__ hbuf,
                                unsigned* __restrict__ flags){
  int tid = blockIdx.x*blockDim.x + threadIdx.x;
  if (tid < 64) flags[tid] = 0u;
  if (tid < BB*DD) hbuf[tid] = (f16)h0[tid];   // hbuf[0][b][e], same layout as h0
}

// ---------------- 128x128 f16 MFMA GEMM, B given as [N,K] (i.e. W[e,d]) ----------------
// out[row,col] = sum_k A[row,k] * Bw[col,k]  (+ epilogue)
__global__ __launch_bounds__(256)
void gemm_f16_kernel(const f16* __restrict__ A, const f16* __restrict__ Bw,
                     float* __restrict__ out32, f16* __restrict__ out16,
                     const float* __restrict__ vec1, const float* __restrict__ vec2,
                     const f16* __restrict__ gxin, int epi)
{
  __shared__ f16 As[128*LDST];
  __shared__ f16 Bs[128*LDST];
  const int K = DD;
  int tid = threadIdx.x;
  int l = tid & 63, w = tid >> 6;
  int wr = w >> 1, wc = w & 1;
  int bm = blockIdx.x, bn = blockIdx.y;

  f32x4 acc[4][4];
  #pragma unroll
  for (int i=0;i<4;++i)
    #pragma unroll
    for (int j=0;j<4;++j)
      acc[i][j] = (f32x4){0.f,0.f,0.f,0.f};

  const int r0 = tid >> 2;   // 0..63
  const int q  = tid & 3;    // 0..3 (16B chunk within a 64B row)

  for (int kt = 0; kt < K/32; ++kt){
    __syncthreads();
    #pragma unroll
    for (int hh=0; hh<2; ++hh){
      int row = hh*64 + r0;
      uint4 va = *(const uint4*)(A  + (size_t)(bm*128+row)*K + kt*32 + q*8);
      uint4 vb = *(const uint4*)(Bw + (size_t)(bn*128+row)*K + kt*32 + q*8);
      *(uint4*)(As + row*LDST + q*8) = va;
      *(uint4*)(Bs + row*LDST + q*8) = vb;
    }
    __syncthreads();
    int lr = l & 15, kg = (l >> 4) * 8;
    f16x8 af[4], bf[4];
    #pragma unroll
    for (int i=0;i<4;++i){
      af[i] = *(const f16x8*)(As + (wr*64 + i*16 + lr)*LDST + kg);
      bf[i] = *(const f16x8*)(Bs + (wc*64 + i*16 + lr)*LDST + kg);
    }
    #pragma unroll
    for (int i=0;i<4;++i)
      #pragma unroll
      for (int j=0;j<4;++j)
        acc[i][j] = __builtin_amdgcn_mfma_f32_16x16x32_f16(af[i], bf[j], acc[i][j], 0,0,0);
  }

  int lr = l & 15, lh = l >> 4;
  #pragma unroll
  for (int i=0;i<4;++i){
    #pragma unroll
    for (int j=0;j<4;++j){
      #pragma unroll
      for (int r=0;r<4;++r){
        int row = bm*128 + wr*64 + i*16 + lh*4 + r;
        int col = bn*128 + wc*64 + j*16 + lr;
        float v = acc[i][j][r];
        size_t off = (size_t)row*DD + col;
        if (epi == 0){                       // wx = x@Wx^T + bias  (f32, stashed in d_out)
          out32[off] = v + vec1[col];
        } else if (epi == 1){                // alpha = exp(-softplus(pre+b_delta)*exp(-exp(A)))
          float pre = v + vec1[col];
          float sp  = (pre > 20.f) ? pre : log1pf(expf(pre));
          float decay = expf(-expf(vec2[col]));
          out32[off] = expf(-sp*decay);
        } else if (epi == 2){                // gx = x@Wgx^T + b_gate  (f16)
          out16[off] = (f16)(v + vec1[col]);
        } else {                             // out = h * silu(acc + gx)
          float g = v + (float)gxin[off];
          float hval = (float)A[off];        // A == h_out_f16
          out32[off] = hval * g / (1.f + expf(-g));
        }
      }
    }
  }
}

// ---------------- recurrence: 64 WGs, slice of 16 e-rows each, flag-synced ----------------
__global__ __launch_bounds__(256)
void rec_kernel(const f16* __restrict__ Rf, const float* __restrict__ wx,
                const float* __restrict__ alpha, const float* __restrict__ h0,
                f16* __restrict__ hbuf, f16* __restrict__ hout,
                unsigned* __restrict__ flags)
{
  __shared__ f16  Rlds[32*64*8];   // 32KB, frag-ordered: chunk c = kt*64+lane, 8 halves each
  __shared__ float plds[4*64*4];   // 4KB per-wave partial C

  int tid = threadIdx.x;
  int l = tid & 63, w = tid >> 6;
  int j = blockIdx.x;              // slice id 0..63
  int e0 = j * 16;

  // Load R slice into LDS in MFMA-fragment order (one-time).
  for (int it=0; it<8; ++it){
    int c = it*256 + tid;          // 0..2047
    int lane = c & 63, kt = c >> 6;
    int e = e0 + (lane & 15);
    int d = kt*32 + (lane >> 4)*8;
    uint4 v = *(const uint4*)(Rf + (size_t)e*DD + d);
    *(uint4*)(Rlds + (size_t)c*8) = v;
  }

  // Per-thread output element mapping (matches MFMA C layout after reduce):
  int lsrc = tid >> 2, reg = tid & 3;
  int rr = ((lsrc >> 4) << 2) + reg;   // e_local 0..15
  int b  = lsrc & 15;                  // batch
  float hstate = h0[(size_t)b*DD + e0 + rr];
  __syncthreads();

  const int myflag = tid & 63;
  for (int t = 0; t < TT; ++t){
    // prefetch wx/alpha for this step (independent of h -> hides HBM latency under spin)
    size_t off = ((size_t)t*BB + b)*DD + e0 + rr;
    float wxv = wx[off];
    float alv = alpha[off];

    if (t > 0){
      unsigned* fp = flags + myflag;
      int guard = 0;
      while (__hip_atomic_load(fp, __ATOMIC_RELAXED, __HIP_MEMORY_SCOPE_AGENT) < (unsigned)t
             && guard < 50000){
        ++guard;
        __builtin_amdgcn_s_sleep(1);
      }
      __threadfence();   // acquire: invalidate caches so h reads are fresh
    }

    const f16* hb = hbuf + (size_t)(t & 1) * (BB*DD);
    f32x4 acc = (f32x4){0.f,0.f,0.f,0.f};
    #pragma unroll
    for (int kk=0; kk<8; ++kk){
      int kt = w*8 + kk;   // this wave's K range
      f16x8 a     = *(const f16x8*)(Rlds + ((size_t)kt*64 + l)*8);
      f16x8 bfrag = *(const f16x8*)(hb + (size_t)(l & 15)*DD + kt*32 + ((l >> 4)*8));
      acc = __builtin_amdgcn_mfma_f32_16x16x32_f16(a, bfrag, acc, 0, 0, 0);
    }
    *(f32x4*)(plds + ((size_t)w*64 + l)*4) = acc;
    __syncthreads();

    float v = plds[(0*64+lsrc)*4+reg] + plds[(1*64+lsrc)*4+reg]
            + plds[(2*64+lsrc)*4+reg] + plds[(3*64+lsrc)*4+reg];
    float z = v + wxv;
    float cand = tanhf(z);
    float hn = alv*hstate + (1.f - alv)*cand;
    hstate = hn;
    f16 h16 = (f16)hn;
    f16* hw = hbuf + (size_t)((t+1) & 1) * (BB*DD);
    hw[(size_t)b*DD + e0 + rr] = h16;
    hout[off] = h16;

    __threadfence();       // release: flush h stores to LLC
    __syncthreads();       // all threads' stores fenced before publish; also protects plds reuse
    if (tid == 0)
      __hip_atomic_store(flags + j, (unsigned)(t+1), __ATOMIC_RELAXED, __HIP_MEMORY_SCOPE_AGENT);
  }
}

// ---------------- host launcher ----------------
extern "C" void kernel_launch(void* const* d_in, const int* in_sizes, int n_in,
                              void* d_out, int out_size, void* d_ws, size_t ws_size,
                              hipStream_t stream)
{
  const float* x    = (const float*)d_in[0];
  const float* h0   = (const float*)d_in[1];
  const float* Wx   = (const float*)d_in[2];
  const float* R    = (const float*)d_in[3];
  const float* bias = (const float*)d_in[4];
  const float* Wd   = (const float*)d_in[5];
  const float* bd   = (const float*)d_in[6];
  const float* Aar  = (const float*)d_in[7];
  const float* Wgx  = (const float*)d_in[8];
  const float* Wgh  = (const float*)d_in[9];
  const float* bg   = (const float*)d_in[10];
  float* out = (float*)d_out;

  char* ws = (char*)d_ws;
  size_t off = 0;
  auto carve = [&](size_t bytes) -> void* {
    void* p = ws + off;
    off += (bytes + 255) & ~(size_t)255;
    return p;
  };
  f16* x16    = (f16*)carve((size_t)MM*DD*2);
  f16* Wx16   = (f16*)carve((size_t)DD*DD*2);
  f16* Wd16   = (f16*)carve((size_t)DD*DD*2);
  f16* Wgx16  = (f16*)carve((size_t)DD*DD*2);
  f16* Wgh16  = (f16*)carve((size_t)DD*DD*2);
  f16* R16    = (f16*)carve((size_t)DD*DD*2);
  float* alphaB = (float*)carve((size_t)MM*DD*4);
  f16* gx16   = (f16*)carve((size_t)MM*DD*2);
  f16* hout16 = (f16*)carve((size_t)MM*DD*2);
  f16* hbuf   = (f16*)carve((size_t)2*BB*DD*2);
  unsigned* flags = (unsigned*)carve(256);
  if (off > ws_size) return;  // ws too small: leave d_out poisoned (visible failure)

  float* wxbuf = out;  // stash wx in d_out; final GEMM overwrites it

  cvt_kernel<<<1024, 256, 0, stream>>>(x,   x16,   MM*DD/4);
  cvt_kernel<<<256,  256, 0, stream>>>(Wx,  Wx16,  DD*DD/4);
  cvt_kernel<<<256,  256, 0, stream>>>(Wd,  Wd16,  DD*DD/4);
  cvt_kernel<<<256,  256, 0, stream>>>(Wgx, Wgx16, DD*DD/4);
  cvt_kernel<<<256,  256, 0, stream>>>(Wgh, Wgh16, DD*DD/4);
  cvt_kernel<<<256,  256, 0, stream>>>(R,   R16,   DD*DD/4);
  init_rec_kernel<<<64, 256, 0, stream>>>(h0, hbuf, flags);

  dim3 gg(MM/128, DD/128);
  gemm_f16_kernel<<<gg, 256, 0, stream>>>(x16, Wx16,  wxbuf,  nullptr, bias, nullptr, nullptr, 0);
  gemm_f16_kernel<<<gg, 256, 0, stream>>>(x16, Wd16,  alphaB, nullptr, bd,   Aar,     nullptr, 1);
  gemm_f16_kernel<<<gg, 256, 0, stream>>>(x16, Wgx16, nullptr, gx16,   bg,   nullptr, nullptr, 2);

  rec_kernel<<<64, 256, 0, stream>>>(R16, wxbuf, alphaB, h0, hbuf, hout16, flags);

  gemm_f16_kernel<<<gg, 256, 0, stream>>>(hout16, Wgh16, out, nullptr, nullptr, nullptr, gx16, 3);
}

// Round 2
// 9612.216 us; speedup vs baseline: 2.9555x; 2.9555x over previous
//
#include <hip/hip_runtime.h>
#include <cstdint>
#include <cstddef>

typedef _Float16 f16;
typedef _Float16 f16x8 __attribute__((ext_vector_type(8)));
typedef _Float16 f16x4v __attribute__((ext_vector_type(4)));
typedef float f32x4 __attribute__((ext_vector_type(4)));

#define TT 2048
#define BB 16
#define DD 1024
#define MM (TT*BB)
#define LDST 40   // padded LDS row stride (halves) to break bank conflicts

// ---------------- f32 -> f16 convert ----------------
__global__ void cvt_kernel(const float* __restrict__ in, f16* __restrict__ out, int n4){
  int stride = gridDim.x * blockDim.x;
  for (int j = blockIdx.x*blockDim.x + threadIdx.x; j < n4; j += stride){
    float4 v = ((const float4*)in)[j];
    f16x4v o;
    o[0]=(f16)v.x; o[1]=(f16)v.y; o[2]=(f16)v.z; o[3]=(f16)v.w;
    ((f16x4v*)out)[j] = o;
  }
}

// ---------------- recurrence init: zero flags, h0 -> hbuf[0] ----------------
__global__ void init_rec_kernel(const float* __restrict__ h0, f16* __restrict__ hbuf,
                                unsigned* __restrict__ flags){
  int tid = blockIdx.x*blockDim.x + threadIdx.x;
  if (tid < 64) flags[tid] = 0u;
  if (tid < BB*DD) hbuf[tid] = (f16)h0[tid];   // hbuf[0][b][e], same layout as h0
}

// ---------------- 128x128 f16 MFMA GEMM, B given as [N,K] (i.e. W[e,d]) ----------------
// out[row,col] = sum_k A[row,k] * Bw[col,k]  (+ epilogue)
__global__ __launch_bounds__(256)
void gemm_f16_kernel(const f16* __restrict__ A, const f16* __restrict__ Bw,
                     float* __restrict__ out32, f16* __restrict__ out16,
                     const float* __restrict__ vec1, const float* __restrict__ vec2,
                     const f16* __restrict__ gxin, int epi)
{
  __shared__ f16 As[128*LDST];
  __shared__ f16 Bs[128*LDST];
  const int K = DD;
  int tid = threadIdx.x;
  int l = tid & 63, w = tid >> 6;
  int wr = w >> 1, wc = w & 1;
  int bm = blockIdx.x, bn = blockIdx.y;

  f32x4 acc[4][4];
  #pragma unroll
  for (int i=0;i<4;++i)
    #pragma unroll
    for (int j=0;j<4;++j)
      acc[i][j] = (f32x4){0.f,0.f,0.f,0.f};

  const int r0 = tid >> 2;   // 0..63
  const int q  = tid & 3;    // 0..3 (16B chunk within a 64B row)

  for (int kt = 0; kt < K/32; ++kt){
    __syncthreads();
    #pragma unroll
    for (int hh=0; hh<2; ++hh){
      int row = hh*64 + r0;
      uint4 va = *(const uint4*)(A  + (size_t)(bm*128+row)*K + kt*32 + q*8);
      uint4 vb = *(const uint4*)(Bw + (size_t)(bn*128+row)*K + kt*32 + q*8);
      *(uint4*)(As + row*LDST + q*8) = va;
      *(uint4*)(Bs + row*LDST + q*8) = vb;
    }
    __syncthreads();
    int lr = l & 15, kg = (l >> 4) * 8;
    f16x8 af[4], bf[4];
    #pragma unroll
    for (int i=0;i<4;++i){
      af[i] = *(const f16x8*)(As + (wr*64 + i*16 + lr)*LDST + kg);
      bf[i] = *(const f16x8*)(Bs + (wc*64 + i*16 + lr)*LDST + kg);
    }
    #pragma unroll
    for (int i=0;i<4;++i)
      #pragma unroll
      for (int j=0;j<4;++j)
        acc[i][j] = __builtin_amdgcn_mfma_f32_16x16x32_f16(af[i], bf[j], acc[i][j], 0,0,0);
  }

  int lr = l & 15, lh = l >> 4;
  #pragma unroll
  for (int i=0;i<4;++i){
    #pragma unroll
    for (int j=0;j<4;++j){
      #pragma unroll
      for (int r=0;r<4;++r){
        int row = bm*128 + wr*64 + i*16 + lh*4 + r;
        int col = bn*128 + wc*64 + j*16 + lr;
        float v = acc[i][j][r];
        size_t off = (size_t)row*DD + col;
        if (epi == 0){                       // wx = x@Wx^T + bias  (f32, stashed in d_out)
          out32[off] = v + vec1[col];
        } else if (epi == 1){                // alpha = exp(-softplus(pre+b_delta)*exp(-exp(A)))
          float pre = v + vec1[col];
          float sp  = (pre > 20.f) ? pre : log1pf(expf(pre));
          float decay = expf(-expf(vec2[col]));
          out32[off] = expf(-sp*decay);
        } else if (epi == 2){                // gx = x@Wgx^T + b_gate  (f16)
          out16[off] = (f16)(v + vec1[col]);
        } else {                             // out = h * silu(acc + gx)
          float g = v + (float)gxin[off];
          float hval = (float)A[off];        // A == h_out_f16
          out32[off] = hval * g / (1.f + expf(-g));
        }
      }
    }
  }
}

// ---------------- recurrence: 64 WGs, slice of 16 e-rows each, flag-synced ----------------
// Sync protocol (no __threadfence — targeted coherence only):
//   release: coherent (sc0 sc1) h stores -> s_waitcnt vmcnt(0) -> __syncthreads -> flag store (AGENT)
//   acquire: spin on flag (AGENT atomic load) -> coherent (sc0 sc1) h loads
__global__ __launch_bounds__(256)
void rec_kernel(const f16* __restrict__ Rf, const float* __restrict__ wx,
                const float* __restrict__ alpha, const float* __restrict__ h0,
                f16* __restrict__ hbuf, f16* __restrict__ hout,
                unsigned* __restrict__ flags)
{
  __shared__ f16  Rlds[32*64*8];   // 32KB, frag-ordered: chunk c = kt*64+lane, 8 halves each
  __shared__ float plds[4*64*4];   // 4KB per-wave partial C

  int tid = threadIdx.x;
  int l = tid & 63, w = tid >> 6;
  int j = blockIdx.x;              // slice id 0..63
  int e0 = j * 16;

  // Load R slice into LDS in MFMA-fragment order (one-time).
  for (int it=0; it<8; ++it){
    int c = it*256 + tid;          // 0..2047
    int lane = c & 63, kt = c >> 6;
    int e = e0 + (lane & 15);
    int d = kt*32 + (lane >> 4)*8;
    uint4 v = *(const uint4*)(Rf + (size_t)e*DD + d);
    *(uint4*)(Rlds + (size_t)c*8) = v;
  }

  // Per-thread output element mapping (matches MFMA C layout after reduce):
  int lsrc = tid >> 2, reg = tid & 3;
  int rr = ((lsrc >> 4) << 2) + reg;   // e_local 0..15
  int b  = lsrc & 15;                  // batch
  float hstate = h0[(size_t)b*DD + e0 + rr];
  __syncthreads();

  const int myflag = tid & 63;
  for (int t = 0; t < TT; ++t){
    // prefetch wx/alpha for this step (independent of h -> hides HBM latency under spin)
    size_t off = ((size_t)t*BB + b)*DD + e0 + rr;
    float wxv = wx[off];
    float alv = alpha[off];

    if (t > 0){
      unsigned* fp = flags + myflag;
      int guard = 0;
      // wave exits only when ALL lanes' flags reach t (divergent loop, exec-masked)
      while (__hip_atomic_load(fp, __ATOMIC_RELAXED, __HIP_MEMORY_SCOPE_AGENT) < (unsigned)t
             && guard < 200000){
        ++guard;
        __builtin_amdgcn_s_sleep(1);
      }
    }

    const f16* hb = hbuf + (size_t)(t & 1) * (BB*DD);
    // coherent vector loads of h fragments (bypass stale L1/L2, read LLC)
    f16x8 bfrag[8];
    #pragma unroll
    for (int kk=0; kk<8; ++kk){
      int kt = w*8 + kk;   // this wave's K range
      const f16* hp = hb + (size_t)(l & 15)*DD + kt*32 + ((l >> 4)*8);
      asm volatile("global_load_dwordx4 %0, %1, off sc0 sc1"
                   : "=v"(bfrag[kk]) : "v"(hp) : "memory");
    }
    asm volatile("s_waitcnt vmcnt(0)" ::: "memory");
    __builtin_amdgcn_sched_barrier(0);

    f32x4 acc = (f32x4){0.f,0.f,0.f,0.f};
    #pragma unroll
    for (int kk=0; kk<8; ++kk){
      int kt = w*8 + kk;
      f16x8 a = *(const f16x8*)(Rlds + ((size_t)kt*64 + l)*8);
      acc = __builtin_amdgcn_mfma_f32_16x16x32_f16(a, bfrag[kk], acc, 0, 0, 0);
    }
    *(f32x4*)(plds + ((size_t)w*64 + l)*4) = acc;
    __syncthreads();

    float v = plds[(0*64+lsrc)*4+reg] + plds[(1*64+lsrc)*4+reg]
            + plds[(2*64+lsrc)*4+reg] + plds[(3*64+lsrc)*4+reg];
    float z = v + wxv;
    float cand = tanhf(z);
    float hn = alv*hstate + (1.f - alv)*cand;
    hstate = hn;
    f16 h16 = (f16)hn;

    // coherent h store (write-through to LLC) + plain hout store
    f16* hw = hbuf + (size_t)((t+1) & 1) * (BB*DD) + (size_t)b*DD + e0 + rr;
    unsigned hbits = (unsigned)*(unsigned short*)&h16;
    asm volatile("global_store_short %0, %1, off sc0 sc1"
                 :: "v"(hw), "v"(hbits) : "memory");
    hout[off] = h16;

    // release: drain stores to coherent point, then publish
    asm volatile("s_waitcnt vmcnt(0)" ::: "memory");
    __syncthreads();       // all threads drained; also protects plds reuse
    if (tid == 0)
      __hip_atomic_store(flags + j, (unsigned)(t+1), __ATOMIC_RELAXED, __HIP_MEMORY_SCOPE_AGENT);
  }
}

// ---------------- host launcher ----------------
extern "C" void kernel_launch(void* const* d_in, const int* in_sizes, int n_in,
                              void* d_out, int out_size, void* d_ws, size_t ws_size,
                              hipStream_t stream)
{
  const float* x    = (const float*)d_in[0];
  const float* h0   = (const float*)d_in[1];
  const float* Wx   = (const float*)d_in[2];
  const float* R    = (const float*)d_in[3];
  const float* bias = (const float*)d_in[4];
  const float* Wd   = (const float*)d_in[5];
  const float* bd   = (const float*)d_in[6];
  const float* Aar  = (const float*)d_in[7];
  const float* Wgx  = (const float*)d_in[8];
  const float* Wgh  = (const float*)d_in[9];
  const float* bg   = (const float*)d_in[10];
  float* out = (float*)d_out;

  char* ws = (char*)d_ws;
  size_t off = 0;
  auto carve = [&](size_t bytes) -> void* {
    void* p = ws + off;
    off += (bytes + 255) & ~(size_t)255;
    return p;
  };
  f16* x16    = (f16*)carve((size_t)MM*DD*2);
  f16* Wx16   = (f16*)carve((size_t)DD*DD*2);
  f16* Wd16   = (f16*)carve((size_t)DD*DD*2);
  f16* Wgx16  = (f16*)carve((size_t)DD*DD*2);
  f16* Wgh16  = (f16*)carve((size_t)DD*DD*2);
  f16* R16    = (f16*)carve((size_t)DD*DD*2);
  float* alphaB = (float*)carve((size_t)MM*DD*4);
  f16* gx16   = (f16*)carve((size_t)MM*DD*2);
  f16* hout16 = (f16*)carve((size_t)MM*DD*2);
  f16* hbuf   = (f16*)carve((size_t)2*BB*DD*2);
  unsigned* flags = (unsigned*)carve(256);
  if (off > ws_size) return;  // ws too small: leave d_out poisoned (visible failure)

  float* wxbuf = out;  // stash wx in d_out; final GEMM overwrites it

  cvt_kernel<<<1024, 256, 0, stream>>>(x,   x16,   MM*DD/4);
  cvt_kernel<<<256,  256, 0, stream>>>(Wx,  Wx16,  DD*DD/4);
  cvt_kernel<<<256,  256, 0, stream>>>(Wd,  Wd16,  DD*DD/4);
  cvt_kernel<<<256,  256, 0, stream>>>(Wgx, Wgx16, DD*DD/4);
  cvt_kernel<<<256,  256, 0, stream>>>(Wgh, Wgh16, DD*DD/4);
  cvt_kernel<<<256,  256, 0, stream>>>(R,   R16,   DD*DD/4);
  init_rec_kernel<<<64, 256, 0, stream>>>(h0, hbuf, flags);

  dim3 gg(MM/128, DD/128);
  gemm_f16_kernel<<<gg, 256, 0, stream>>>(x16, Wx16,  wxbuf,  nullptr, bias, nullptr, nullptr, 0);
  gemm_f16_kernel<<<gg, 256, 0, stream>>>(x16, Wd16,  alphaB, nullptr, bd,   Aar,     nullptr, 1);
  gemm_f16_kernel<<<gg, 256, 0, stream>>>(x16, Wgx16, nullptr, gx16,   bg,   nullptr, nullptr, 2);

  rec_kernel<<<64, 256, 0, stream>>>(R16, wxbuf, alphaB, h0, hbuf, hout16, flags);

  gemm_f16_kernel<<<gg, 256, 0, stream>>>(hout16, Wgh16, out, nullptr, nullptr, nullptr, gx16, 3);
}

// Round 5
// 8054.739 us; speedup vs baseline: 3.5270x; 1.1934x over previous
//
#include <hip/hip_runtime.h>
#include <cstdint>
#include <cstddef>

typedef _Float16 f16;
typedef _Float16 f16x8 __attribute__((ext_vector_type(8)));
typedef _Float16 f16x4v __attribute__((ext_vector_type(4)));
typedef float f32x4 __attribute__((ext_vector_type(4)));
typedef unsigned uint2v __attribute__((ext_vector_type(2)));

#define TT 2048
#define BB 16
#define DD 1024
#define MM (TT*BB)
#define LDST 40   // padded LDS row stride (halves) to break bank conflicts
#define FPAD 16   // flag padding: one flag per 64B line

// ---------------- f32 -> f16 convert ----------------
__global__ void cvt_kernel(const float* __restrict__ in, f16* __restrict__ out, int n4){
  int stride = gridDim.x * blockDim.x;
  for (int j = blockIdx.x*blockDim.x + threadIdx.x; j < n4; j += stride){
    float4 v = ((const float4*)in)[j];
    f16x4v o;
    o[0]=(f16)v.x; o[1]=(f16)v.y; o[2]=(f16)v.z; o[3]=(f16)v.w;
    ((f16x4v*)out)[j] = o;
  }
}

// ---------------- recurrence init: zero flags, h0 -> hbuf[0] ----------------
__global__ void init_rec_kernel(const float* __restrict__ h0, f16* __restrict__ hbuf,
                                unsigned* __restrict__ flags){
  int tid = blockIdx.x*blockDim.x + threadIdx.x;
  if (tid < 64*FPAD) flags[tid] = 0u;
  if (tid < BB*DD) hbuf[tid] = (f16)h0[tid];   // hbuf[0][b][e], same layout as h0
}

// ---------------- 128x128 f16 MFMA GEMM, B given as [N,K] (i.e. W[e,d]) ----------------
// out[row,col] = sum_k A[row,k] * Bw[col,k]  (+ epilogue)
__global__ __launch_bounds__(256)
void gemm_f16_kernel(const f16* __restrict__ A, const f16* __restrict__ Bw,
                     float* __restrict__ out32, f16* __restrict__ out16,
                     const float* __restrict__ vec1, const float* __restrict__ vec2,
                     const f16* __restrict__ gxin, int epi)
{
  __shared__ f16 As[128*LDST];
  __shared__ f16 Bs[128*LDST];
  const int K = DD;
  int tid = threadIdx.x;
  int l = tid & 63, w = tid >> 6;
  int wr = w >> 1, wc = w & 1;
  int bm = blockIdx.x, bn = blockIdx.y;

  f32x4 acc[4][4];
  #pragma unroll
  for (int i=0;i<4;++i)
    #pragma unroll
    for (int j=0;j<4;++j)
      acc[i][j] = (f32x4){0.f,0.f,0.f,0.f};

  const int r0 = tid >> 2;   // 0..63
  const int q  = tid & 3;    // 0..3 (16B chunk within a 64B row)

  for (int kt = 0; kt < K/32; ++kt){
    __syncthreads();
    #pragma unroll
    for (int hh=0; hh<2; ++hh){
      int row = hh*64 + r0;
      uint4 va = *(const uint4*)(A  + (size_t)(bm*128+row)*K + kt*32 + q*8);
      uint4 vb = *(const uint4*)(Bw + (size_t)(bn*128+row)*K + kt*32 + q*8);
      *(uint4*)(As + row*LDST + q*8) = va;
      *(uint4*)(Bs + row*LDST + q*8) = vb;
    }
    __syncthreads();
    int lr = l & 15, kg = (l >> 4) * 8;
    f16x8 af[4], bf[4];
    #pragma unroll
    for (int i=0;i<4;++i){
      af[i] = *(const f16x8*)(As + (wr*64 + i*16 + lr)*LDST + kg);
      bf[i] = *(const f16x8*)(Bs + (wc*64 + i*16 + lr)*LDST + kg);
    }
    #pragma unroll
    for (int i=0;i<4;++i)
      #pragma unroll
      for (int j=0;j<4;++j)
        acc[i][j] = __builtin_amdgcn_mfma_f32_16x16x32_f16(af[i], bf[j], acc[i][j], 0,0,0);
  }

  int lr = l & 15, lh = l >> 4;
  #pragma unroll
  for (int i=0;i<4;++i){
    #pragma unroll
    for (int j=0;j<4;++j){
      #pragma unroll
      for (int r=0;r<4;++r){
        int row = bm*128 + wr*64 + i*16 + lh*4 + r;
        int col = bn*128 + wc*64 + j*16 + lr;
        float v = acc[i][j][r];
        size_t off = (size_t)row*DD + col;
        if (epi == 0){                       // wx = x@Wx^T + bias  (f32, stashed in d_out)
          out32[off] = v + vec1[col];
        } else if (epi == 1){                // alpha = exp(-softplus(pre+b_delta)*exp(-exp(A)))
          float pre = v + vec1[col];
          float sp  = (pre > 20.f) ? pre : log1pf(expf(pre));
          float decay = expf(-expf(vec2[col]));
          out32[off] = expf(-sp*decay);
        } else if (epi == 2){                // gx = x@Wgx^T + b_gate  (f16)
          out16[off] = (f16)(v + vec1[col]);
        } else {                             // out = h * silu(acc + gx)
          float g = v + (float)gxin[off];
          float hval = (float)A[off];        // A == h_out_f16
          out32[off] = hval * g / (1.f + expf(-g));
        }
      }
    }
  }
}

// ---------------- recurrence: 64 WGs, slice of 16 e-rows each, flag-synced ----------------
// Wave-0-only sync protocol:
//   acquire: wave0 lane l polls flags[l*FPAD] (AGENT atomic) until all >= t,
//            then plain-loads wx/alpha (completes under MFMA); __syncthreads releases waves 1-3
//   compute: all 4 waves do coherent h-fragment loads + MFMA; waves 1-3 dump partials to LDS
//   release: wave0 reduces + pointwise, ONE 8B coherent h store per lane, vmcnt(0), lane0 publishes flag
__global__ __launch_bounds__(256)
void rec_kernel(const f16* __restrict__ Rf, const float* __restrict__ wx,
                const float* __restrict__ alpha, const float* __restrict__ h0,
                f16* __restrict__ hbuf, f16* __restrict__ hout,
                unsigned* __restrict__ flags)
{
  __shared__ f16  Rlds[32*64*8];   // 32KB, frag-ordered: chunk c = kt*64+lane, 8 halves each
  __shared__ float plds[3*64*4];   // waves 1-3 partial C

  int tid = threadIdx.x;
  int l = tid & 63, w = tid >> 6;
  int j = blockIdx.x;              // slice id 0..63
  int e0 = j * 16;

  // Load R slice into LDS in MFMA-fragment order (one-time).
  for (int it=0; it<8; ++it){
    int c = it*256 + tid;          // 0..2047
    int lane = c & 63, kt = c >> 6;
    int e = e0 + (lane & 15);
    int d = kt*32 + (lane >> 4)*8;
    uint4 v = *(const uint4*)(Rf + (size_t)e*DD + d);
    *(uint4*)(Rlds + (size_t)c*8) = v;
  }

  // wave0 per-lane output mapping: lane l owns (b = l&15, e = e0 + rr0..rr0+3)
  int b = l & 15, rr0 = (l >> 4) * 4;
  float4 hstate = {0.f,0.f,0.f,0.f};
  if (w == 0)
    hstate = *(const float4*)(h0 + (size_t)b*DD + e0 + rr0);
  __syncthreads();

  for (int t = 0; t < TT; ++t){
    f32x4 wxv, alv;
    size_t off4 = ((size_t)t*BB + b)*DD + e0 + rr0;
    if (w == 0){
      if (t > 0){
        const unsigned* fp = flags + l*FPAD;
        int guard = 0;
        unsigned long long notready = 1ull;
        while (notready && guard < 1000000){
          unsigned fv = __hip_atomic_load(fp, __ATOMIC_RELAXED, __HIP_MEMORY_SCOPE_AGENT);
          notready = __ballot(fv < (unsigned)t);
          ++guard;
          if (notready) __builtin_amdgcn_s_sleep(1);
        }
      }
      // wx/alpha loads AFTER the spin, BEFORE the barrier: plain loads (compiler
      // manages waitcnt -> always correct); they complete under h-loads + MFMA,
      // consumed only in the epilogue ~1400cy later.
      wxv = *(const f32x4*)(wx + off4);
      alv = *(const f32x4*)(alpha + off4);
    } else {
      wxv = (f32x4){0,0,0,0};
      alv = (f32x4){0,0,0,0};
    }
    __syncthreads();   // waves 1-3 released once wave0 has seen all flags

    const f16* hb = hbuf + (size_t)(t & 1) * (BB*DD);
    // coherent vector loads of h fragments (bypass stale L1/L2, read LLC)
    f16x8 bfrag[8];
    #pragma unroll
    for (int kk=0; kk<8; ++kk){
      int kt = w*8 + kk;   // this wave's K range
      const f16* hp = hb + (size_t)(l & 15)*DD + kt*32 + ((l >> 4)*8);
      asm volatile("global_load_dwordx4 %0, %1, off sc0 sc1"
                   : "=v"(bfrag[kk]) : "v"(hp) : "memory");
    }
    asm volatile("s_waitcnt vmcnt(0)" ::: "memory");
    __builtin_amdgcn_sched_barrier(0);

    f32x4 acc = (f32x4){0.f,0.f,0.f,0.f};
    #pragma unroll
    for (int kk=0; kk<8; ++kk){
      int kt = w*8 + kk;
      f16x8 a = *(const f16x8*)(Rlds + ((size_t)kt*64 + l)*8);
      acc = __builtin_amdgcn_mfma_f32_16x16x32_f16(a, bfrag[kk], acc, 0, 0, 0);
    }
    if (w) *(f32x4*)(plds + ((size_t)(w-1)*64 + l)*4) = acc;
    __syncthreads();   // partials visible to wave0; plds not rewritten until waves 1-3
                       // pass next iteration's first barrier (after wave0's epilogue)

    if (w == 0){
      f32x4 v = acc;
      #pragma unroll
      for (int q=0;q<3;++q)
        v += *(const f32x4*)(plds + ((size_t)q*64 + l)*4);

      f16x4v h4;
      float hs[4] = {hstate.x, hstate.y, hstate.z, hstate.w};
      #pragma unroll
      for (int r=0;r<4;++r){
        float z = v[r] + wxv[r];
        float cand = tanhf(z);
        float hn = alv[r]*hs[r] + (1.f - alv[r])*cand;
        hs[r] = hn;
        h4[r] = (f16)hn;
      }
      hstate = (float4){hs[0], hs[1], hs[2], hs[3]};

      // ONE 8B coherent h store per lane (write-through to LLC)
      f16* hw = hbuf + (size_t)((t+1) & 1) * (BB*DD) + (size_t)b*DD + e0 + rr0;
      uint2v hv = __builtin_bit_cast(uint2v, h4);
      asm volatile("global_store_dwordx2 %0, %1, off sc0 sc1"
                   :: "v"(hw), "v"(hv) : "memory");
      asm volatile("s_waitcnt vmcnt(0)" ::: "memory");   // drain before publish
      if (l == 0)
        __hip_atomic_store(flags + j*FPAD, (unsigned)(t+1),
                           __ATOMIC_RELAXED, __HIP_MEMORY_SCOPE_AGENT);
      // hout store off the critical path (plain cached store)
      *(f16x4v*)(hout + off4) = h4;
    }
  }
}

// ---------------- host launcher ----------------
extern "C" void kernel_launch(void* const* d_in, const int* in_sizes, int n_in,
                              void* d_out, int out_size, void* d_ws, size_t ws_size,
                              hipStream_t stream)
{
  const float* x    = (const float*)d_in[0];
  const float* h0   = (const float*)d_in[1];
  const float* Wx   = (const float*)d_in[2];
  const float* R    = (const float*)d_in[3];
  const float* bias = (const float*)d_in[4];
  const float* Wd   = (const float*)d_in[5];
  const float* bd   = (const float*)d_in[6];
  const float* Aar  = (const float*)d_in[7];
  const float* Wgx  = (const float*)d_in[8];
  const float* Wgh  = (const float*)d_in[9];
  const float* bg   = (const float*)d_in[10];
  float* out = (float*)d_out;

  char* ws = (char*)d_ws;
  size_t off = 0;
  auto carve = [&](size_t bytes) -> void* {
    void* p = ws + off;
    off += (bytes + 255) & ~(size_t)255;
    return p;
  };
  f16* x16    = (f16*)carve((size_t)MM*DD*2);
  f16* Wx16   = (f16*)carve((size_t)DD*DD*2);
  f16* Wd16   = (f16*)carve((size_t)DD*DD*2);
  f16* Wgx16  = (f16*)carve((size_t)DD*DD*2);
  f16* Wgh16  = (f16*)carve((size_t)DD*DD*2);
  f16* R16    = (f16*)carve((size_t)DD*DD*2);
  float* alphaB = (float*)carve((size_t)MM*DD*4);
  f16* gx16   = (f16*)carve((size_t)MM*DD*2);
  f16* hout16 = (f16*)carve((size_t)MM*DD*2);
  f16* hbuf   = (f16*)carve((size_t)2*BB*DD*2);
  unsigned* flags = (unsigned*)carve(64*FPAD*4);
  if (off > ws_size) return;  // ws too small: leave d_out poisoned (visible failure)

  float* wxbuf = out;  // stash wx in d_out; final GEMM overwrites it

  cvt_kernel<<<1024, 256, 0, stream>>>(x,   x16,   MM*DD/4);
  cvt_kernel<<<256,  256, 0, stream>>>(Wx,  Wx16,  DD*DD/4);
  cvt_kernel<<<256,  256, 0, stream>>>(Wd,  Wd16,  DD*DD/4);
  cvt_kernel<<<256,  256, 0, stream>>>(Wgx, Wgx16, DD*DD/4);
  cvt_kernel<<<256,  256, 0, stream>>>(Wgh, Wgh16, DD*DD/4);
  cvt_kernel<<<256,  256, 0, stream>>>(R,   R16,   DD*DD/4);
  init_rec_kernel<<<64, 256, 0, stream>>>(h0, hbuf, flags);

  dim3 gg(MM/128, DD/128);
  gemm_f16_kernel<<<gg, 256, 0, stream>>>(x16, Wx16,  wxbuf,  nullptr, bias, nullptr, nullptr, 0);
  gemm_f16_kernel<<<gg, 256, 0, stream>>>(x16, Wd16,  alphaB, nullptr, bd,   Aar,     nullptr, 1);
  gemm_f16_kernel<<<gg, 256, 0, stream>>>(x16, Wgx16, nullptr, gx16,   bg,   nullptr, nullptr, 2);

  rec_kernel<<<64, 256, 0, stream>>>(R16, wxbuf, alphaB, h0, hbuf, hout16, flags);

  gemm_f16_kernel<<<gg, 256, 0, stream>>>(hout16, Wgh16, out, nullptr, nullptr, nullptr, gx16, 3);
}